// Round 1
// baseline (218.659 us; speedup 1.0000x reference)
//
#include <hip/hip_runtime.h>
#include <hip/hip_bf16.h>

namespace {
constexpr int B_  = 4;
constexpr int C_  = 256;
constexpr int H_  = 80;
constexpr int W1_ = 184;
constexpr int W2_ = 184;
constexpr int G_  = 2;
constexpr int S_  = 9;
constexpr int L_  = 4;
constexpr int CH  = L_ * G_ * S_;   // 72 output channels
constexpr int TM  = 64;             // w1 rows per block
constexpr int TNP = 192;            // padded w2 (184 -> 192)
constexpr int KC  = 16;             // K chunk
constexpr int NCHUNK = C_ / KC;     // 16
// LDS union:
//   staging : As[16][64] floats [0,1024)   Bs[16][192] floats [1024,4096)
//   epilogue: corrS[16][192] floats [0,3072)  pyr[16][161] floats [3072,5648)
constexpr int LDS_FLOATS = 5648;
}

#define GLOBAL_AS __attribute__((address_space(1)))
#define LDS_AS    __attribute__((address_space(3)))

__global__ __launch_bounds__(256, 2)
void corr1d_fused(const float* __restrict__ fmap1, const float* __restrict__ fmap2,
                  const float* __restrict__ coords, const float* __restrict__ sigma,
                  float* __restrict__ out)
{
    __shared__ float lds[LDS_FLOATS];

    const int tile   = blockIdx.x;        // 0..2
    const int bh     = blockIdx.y;        // 0..B*H-1
    const int b      = bh / H_;
    const int h      = bh - b * H_;
    const int w1base = tile * TM;

    const int tid  = threadIdx.x;
    const int tw2  = tid & 15;            // 16 col-groups of 12
    const int tw1  = tid >> 4;            // 16 row-groups of 4
    const int wave = tid >> 6;
    const int lane = tid & 63;

    float acc[4][12];
    #pragma unroll
    for (int i = 0; i < 4; ++i)
        #pragma unroll
        for (int j = 0; j < 12; ++j) acc[i][j] = 0.f;

    // ---- staging descriptors (global_load_lds: LDS dest = wave-uniform base + lane*16B) ----
    const int maxA = B_*C_*H_*W1_ - 4;
    const int maxB = B_*C_*H_*W2_ - 4;

    // A: wave w covers As floats [w*256, w*256+256) == rows kk=4w..4w+3, cols 0..63
    const int a_kk  = 4*wave + (lane >> 4);
    const int a_col = (lane & 15) * 4;
    const int aOff0 = ((b*C_ + a_kk)*H_ + h)*W1_ + w1base + a_col;
    const int aLds  = wave * 256;                       // float idx, wave-uniform

    // B: 3 loads per wave; flat float f = (wave*3+m)*256 + lane*4 -> kk = f/192, col = f%192
    int bOff0[3], bLdsI[3];
    #pragma unroll
    for (int m = 0; m < 3; ++m) {
        const int f    = (wave*3 + m)*256 + lane*4;
        const int kk   = f / TNP;
        const int col  = f - kk*TNP;
        const int colc = (col < W2_) ? col : 0;         // pad cols read garbage-in-bounds; never consumed
        bOff0[m] = ((b*C_ + kk)*H_ + h)*W2_ + colc;
        bLdsI[m] = 1024 + (wave*3 + m)*256;             // float idx, wave-uniform
    }

    const int stepA = KC * H_ * W1_;
    const int stepB = KC * H_ * W2_;

    // ---- K loop: single-buffered global_load_lds staging + 4x12 register-tile FMA ----
    for (int ck = 0; ck < NCHUNK; ++ck) {
        __syncthreads();                                // prev-iter LDS reads done
        int ga = aOff0 + ck*stepA; ga = (ga > maxA) ? maxA : ga;
        __builtin_amdgcn_global_load_lds((const GLOBAL_AS void*)(fmap1 + ga),
                                         (LDS_AS void*)(lds + aLds), 16, 0, 0);
        #pragma unroll
        for (int m = 0; m < 3; ++m) {
            int gb = bOff0[m] + ck*stepB; gb = (gb > maxB) ? maxB : gb;
            __builtin_amdgcn_global_load_lds((const GLOBAL_AS void*)(fmap2 + gb),
                                             (LDS_AS void*)(lds + bLdsI[m]), 16, 0, 0);
        }
        asm volatile("s_waitcnt vmcnt(0)" ::: "memory");
        __syncthreads();                                // all waves' staging visible

        #pragma unroll
        for (int kk = 0; kk < KC; ++kk) {
            const float4 av  = *(const float4*)(lds + kk*64 + tw1*4);
            const float4 bv0 = *(const float4*)(lds + 1024 + kk*TNP + tw2*12);
            const float4 bv1 = *(const float4*)(lds + 1024 + kk*TNP + tw2*12 + 4);
            const float4 bv2 = *(const float4*)(lds + 1024 + kk*TNP + tw2*12 + 8);
            const float a0 = av.x, a1 = av.y, a2 = av.z, a3 = av.w;
            const float bb[12] = {bv0.x,bv0.y,bv0.z,bv0.w,
                                  bv1.x,bv1.y,bv1.z,bv1.w,
                                  bv2.x,bv2.y,bv2.z,bv2.w};
            #pragma unroll
            for (int j = 0; j < 12; ++j) {
                acc[0][j] = fmaf(a0, bb[j], acc[0][j]);
                acc[1][j] = fmaf(a1, bb[j], acc[1][j]);
                acc[2][j] = fmaf(a2, bb[j], acc[2][j]);
                acc[3][j] = fmaf(a3, bb[j], acc[3][j]);
            }
        }
    }

    __syncthreads();                                    // last compute reads done before LDS reuse

    // ---- fused epilogue: 4 chunks of 16 rows ----
    float* corrS = lds;                                 // [16][192]
    float* pyr   = lds + 3072;                          // [16][161]: lvl1[92] lvl2[46] lvl3[23]
    constexpr float scale = 0.0625f;                    // 1/sqrt(256)

    for (int q = 0; q < 4; ++q) {
        // store this chunk's rows (owned by tw1 in [4q,4q+4))
        if ((tw1 >> 2) == q) {
            const int r0 = (tw1 & 3) * 4;
            #pragma unroll
            for (int i = 0; i < 4; ++i)
                #pragma unroll
                for (int j = 0; j < 12; ++j)
                    corrS[(r0 + i)*TNP + tw2*12 + j] = acc[i][j] * scale;
        }
        __syncthreads();

        // pooled pyramid levels, computed directly from level0 (no inter-level dep)
        for (int e = tid; e < 16*161; e += 256) {
            const int r = e / 161;
            const int p = e - r*161;
            const float* row = corrS + r*TNP;
            float v;
            if (p < 92) {
                const int j = 2*p;
                v = 0.5f * (row[j] + row[j+1]);
            } else if (p < 138) {
                const int j = (p - 92) * 4;
                v = 0.25f * (row[j] + row[j+1] + row[j+2] + row[j+3]);
            } else {
                const int j = (p - 138) * 8;
                v = 0.125f * (row[j]+row[j+1]+row[j+2]+row[j+3]
                             +row[j+4]+row[j+5]+row[j+6]+row[j+7]);
            }
            pyr[r*161 + p] = v;
        }
        __syncthreads();

        // Gaussian sampling: 72 channels x 16 rows; 16 consecutive lanes share a channel -> coalesced stores
        for (int t = tid; t < CH*16; t += 256) {
            const int ch = t >> 4;
            const int r  = t & 15;
            const int w1 = w1base + q*16 + r;
            if (w1 < W1_) {
                const int lvl = ch / (G_*S_);
                const int rem = ch - lvl*(G_*S_);
                const int g   = rem / S_;
                const int s   = rem - g*S_;
                const int cix = ((b*G_ + g)*H_ + h)*W1_ + w1;
                const float x  = (float)(s - S_/2) * sigma[cix] + coords[cix];
                const float xi = x * (1.0f / (float)(1 << lvl)); // exact pow2 scale
                const int   Wl = W2_ >> lvl;
                const float x0 = floorf(xi);
                const float wr = xi - x0;
                const int i0 = (int)x0;
                const int i1 = i0 + 1;
                const float* rowp = (lvl == 0) ? (corrS + r*TNP)
                                  : (pyr + r*161 + ((lvl == 1) ? 0 : (lvl == 2) ? 92 : 138));
                const int i0c = min(max(i0, 0), Wl - 1);
                const int i1c = min(max(i1, 0), Wl - 1);
                const float v0 = (i0 >= 0 && i0 < Wl) ? rowp[i0c] : 0.f;  // zero-pad mask
                const float v1 = (i1 >= 0 && i1 < Wl) ? rowp[i1c] : 0.f;
                out[((b*CH + ch)*H_ + h)*W1_ + w1] = (1.f - wr)*v0 + wr*v1;
            }
        }
        __syncthreads();                                // reads done before next chunk overwrites corrS
    }
}

extern "C" void kernel_launch(void* const* d_in, const int* in_sizes, int n_in,
                              void* d_out, int out_size, void* d_ws, size_t ws_size,
                              hipStream_t stream) {
    const float* fmap1  = (const float*)d_in[0];
    const float* fmap2  = (const float*)d_in[1];
    const float* coords = (const float*)d_in[2];
    const float* sigma  = (const float*)d_in[3];
    float* out = (float*)d_out;

    dim3 grid((W1_ + TM - 1) / TM, B_ * H_);   // 3 x 320
    corr1d_fused<<<grid, 256, 0, stream>>>(fmap1, fmap2, coords, sigma, out);
}